// Round 1
// baseline (99.130 us; speedup 1.0000x reference)
//
#include <hip/hip_runtime.h>

// SubTokenEmbedding: fused embedding gather + sorted-segment sum pooling.
//
// out[s, :] = sum_{i : segs[i]==s} table[ids[i], :]     (segs sorted ascending)
//
// Strategy: one 32-lane group per SPG consecutive segments. Binary-search the
// subtoken range covering those segments, scan it once, accumulate the 128-wide
// row in registers (lane l owns floats [4l, 4l+4)), plain-store each segment
// (zeros for empty segments). No atomics, no output pre-zeroing needed: every
// output element is written exactly once per launch.

#define H_EMB 128
#define LPG   32      // lanes per group (32 lanes x float4 = 128 floats)
#define SPG   8       // segments per group

__global__ __launch_bounds__(256)
void SubTokenEmbedding_6734508720780_kernel(
    const float* __restrict__ table,
    const int*   __restrict__ ids,
    const int*   __restrict__ segs,
    float*       __restrict__ out,
    int total_subtokens, int n_nodes)
{
    const int group = (int)((blockIdx.x * blockDim.x + threadIdx.x) / LPG);
    const int lane  = (int)(threadIdx.x & (LPG - 1));
    const int s0    = group * SPG;
    if (s0 >= n_nodes) return;
    const int s_end = min(s0 + SPG, n_nodes);

    // lower_bound(v): first index i with segs[i] >= v   (all lanes redundant,
    // same-address loads broadcast in one transaction)
    auto lower_bound = [&](int v) -> int {
        int lo = 0, hi = total_subtokens;
        while (lo < hi) {
            int mid = (lo + hi) >> 1;
            if (segs[mid] < v) lo = mid + 1; else hi = mid;
        }
        return lo;
    };
    const int beg = lower_bound(s0);
    const int end = lower_bound(s_end);

    const float* trow_base = table + (size_t)lane * 4;
    float*       orow_base = out   + (size_t)lane * 4;

    float4 acc = make_float4(0.f, 0.f, 0.f, 0.f);
    int cur = s0;

    // batch-load seg/id stream 32 at a time, distribute via shfl
    int batch_base = beg;
    int sv = 0, iv = 0;
    if (batch_base + lane < end) {
        sv = segs[batch_base + lane];
        iv = ids [batch_base + lane];
    }

    for (int j = beg; j < end; ++j) {
        int k = j - batch_base;
        if (k == LPG) {
            batch_base += LPG;
            k = 0;
            if (batch_base + lane < end) {
                sv = segs[batch_base + lane];
                iv = ids [batch_base + lane];
            }
        }
        const int s  = __shfl(sv, k, LPG);
        const int id = __shfl(iv, k, LPG);

        if (s != cur) {
            // flush finished segment, zeros for any empty segments in between
            *reinterpret_cast<float4*>(orow_base + (size_t)cur * H_EMB) = acc;
            acc = make_float4(0.f, 0.f, 0.f, 0.f);
            for (int z = cur + 1; z < s; ++z)
                *reinterpret_cast<float4*>(orow_base + (size_t)z * H_EMB) = acc;
            cur = s;
        }

        const float4 t = *reinterpret_cast<const float4*>(trow_base + (size_t)id * H_EMB);
        acc.x += t.x; acc.y += t.y; acc.z += t.z; acc.w += t.w;
    }

    // final flush: cur, then zeros through s_end-1
    *reinterpret_cast<float4*>(orow_base + (size_t)cur * H_EMB) = acc;
    acc = make_float4(0.f, 0.f, 0.f, 0.f);
    for (int z = cur + 1; z < s_end; ++z)
        *reinterpret_cast<float4*>(orow_base + (size_t)z * H_EMB) = acc;
}

extern "C" void kernel_launch(void* const* d_in, const int* in_sizes, int n_in,
                              void* d_out, int out_size, void* d_ws, size_t ws_size,
                              hipStream_t stream) {
    const float* table = (const float*)d_in[0];
    const int*   ids   = (const int*)d_in[1];
    const int*   segs  = (const int*)d_in[2];
    float*       out   = (float*)d_out;

    const int total_subtokens = in_sizes[1];
    const int n_nodes         = out_size / H_EMB;   // out is [n_nodes, 128]

    const int n_groups         = (n_nodes + SPG - 1) / SPG;
    const int groups_per_block = 256 / LPG;          // 8
    const int n_blocks         = (n_groups + groups_per_block - 1) / groups_per_block;

    SubTokenEmbedding_6734508720780_kernel<<<n_blocks, 256, 0, stream>>>(
        table, ids, segs, out, total_subtokens, n_nodes);
}

// Round 2
// 82.338 us; speedup vs baseline: 1.2039x; 1.2039x over previous
//
#include <hip/hip_runtime.h>

// SubTokenEmbedding: fused embedding gather + sorted-segment sum pooling.
//
// out[s, :] = sum_{i : segs[i]==s} table[ids[i], :]     (segs sorted ascending)
//
// Two kernels:
//   1) build_starts: starts[s] = lower_bound(segs, s) for s in [0, n_nodes],
//      computed by scatter from adjacent-diff of the sorted segs array.
//   2) main: one 32-lane group per SPG consecutive segments; reads its
//      subtoken range from starts[], scans it with 8-deep load ILP,
//      accumulates the 128-wide row in registers (lane l owns floats
//      [4l,4l+4)), plain-stores each segment (zeros for empty segments).
// No atomics; every output element written exactly once per launch, so the
// poisoned d_out needs no pre-zeroing.

#define H_EMB  128
#define LPG    32      // lanes per group (32 lanes x float4 = 128 floats)
#define SPG    4       // segments per group
#define UNROLL 8       // table-row loads kept in flight per group

__global__ __launch_bounds__(256)
void build_starts_kernel(const int* __restrict__ segs, int* __restrict__ starts,
                         int n, int n_nodes)
{
    const int i = blockIdx.x * blockDim.x + threadIdx.x;
    if (i >= n) return;
    const int s  = segs[i];
    const int sp = (i == 0) ? -1 : segs[i - 1];
    for (int seg = sp + 1; seg <= s; ++seg) starts[seg] = i;   // run-starts + empty gaps
    if (i == n - 1)
        for (int seg = s + 1; seg <= n_nodes; ++seg) starts[seg] = n;  // tail sentinel
}

__global__ __launch_bounds__(256)
void SubTokenEmbedding_6734508720780_kernel(
    const float* __restrict__ table,
    const int*   __restrict__ ids,
    const int*   __restrict__ segs,
    const int*   __restrict__ starts,   // [n_nodes+1], or nullptr -> binary search
    float*       __restrict__ out,
    int total_subtokens, int n_nodes)
{
    const int group = (int)((blockIdx.x * blockDim.x + threadIdx.x) / LPG);
    const int lane  = (int)(threadIdx.x & (LPG - 1));
    const int s0    = group * SPG;
    if (s0 >= n_nodes) return;
    const int s_end = min(s0 + SPG, n_nodes);

    int beg, end;
    if (starts) {
        beg = starts[s0];
        end = starts[s_end];
    } else {
        auto lower_bound = [&](int v) -> int {
            int lo = 0, hi = total_subtokens;
            while (lo < hi) {
                int mid = (lo + hi) >> 1;
                if (segs[mid] < v) lo = mid + 1; else hi = mid;
            }
            return lo;
        };
        beg = lower_bound(s0);
        end = lower_bound(s_end);
    }

    const float* trow = table + (size_t)lane * 4;
    float*       orow = out   + (size_t)lane * 4;

    float4 acc = make_float4(0.f, 0.f, 0.f, 0.f);
    int cur = s0;

    // seg/id stream loaded 32 at a time (one coalesced 128B load per group),
    // values distributed to all lanes via shfl.
    int sv = 0, iv = 0;
    if (beg + lane < end) { sv = segs[beg + lane]; iv = ids[beg + lane]; }

    for (int base = beg; base < end; base += LPG) {
        const int cnt = min(LPG, end - base);
        const int nb  = base + LPG;
        int sv2 = 0, iv2 = 0;
        if (nb + lane < end) { sv2 = segs[nb + lane]; iv2 = ids[nb + lane]; }  // prefetch next batch

        for (int k = 0; k < cnt; k += UNROLL) {
            int s_a[UNROLL], id_a[UNROLL];
            #pragma unroll
            for (int u = 0; u < UNROLL; ++u) {
                s_a[u]  = __shfl(sv, k + u, LPG);
                id_a[u] = __shfl(iv, k + u, LPG);
            }
            // issue all UNROLL gathers before consuming any (out-of-range u
            // reads row 0 -- iv defaults to 0 -- harmless and never accumulated)
            float4 t[UNROLL];
            #pragma unroll
            for (int u = 0; u < UNROLL; ++u)
                t[u] = *reinterpret_cast<const float4*>(trow + (size_t)id_a[u] * H_EMB);

            #pragma unroll
            for (int u = 0; u < UNROLL; ++u) {
                if (k + u < cnt) {
                    const int s = s_a[u];
                    if (s != cur) {
                        *reinterpret_cast<float4*>(orow + (size_t)cur * H_EMB) = acc;
                        const float4 zero = make_float4(0.f, 0.f, 0.f, 0.f);
                        for (int z = cur + 1; z < s; ++z)
                            *reinterpret_cast<float4*>(orow + (size_t)z * H_EMB) = zero;
                        acc = zero;
                        cur = s;
                    }
                    acc.x += t[u].x; acc.y += t[u].y; acc.z += t[u].z; acc.w += t[u].w;
                }
            }
        }
        sv = sv2; iv = iv2;
    }

    // final flush: cur, then zeros through s_end-1
    *reinterpret_cast<float4*>(orow + (size_t)cur * H_EMB) = acc;
    const float4 zero = make_float4(0.f, 0.f, 0.f, 0.f);
    for (int z = cur + 1; z < s_end; ++z)
        *reinterpret_cast<float4*>(orow + (size_t)z * H_EMB) = zero;
}

extern "C" void kernel_launch(void* const* d_in, const int* in_sizes, int n_in,
                              void* d_out, int out_size, void* d_ws, size_t ws_size,
                              hipStream_t stream) {
    const float* table = (const float*)d_in[0];
    const int*   ids   = (const int*)d_in[1];
    const int*   segs  = (const int*)d_in[2];
    float*       out   = (float*)d_out;

    const int total_subtokens = in_sizes[1];
    const int n_nodes         = out_size / H_EMB;   // out is [n_nodes, 128]

    int* starts = nullptr;
    if (ws_size >= (size_t)(n_nodes + 1) * sizeof(int)) {
        starts = (int*)d_ws;
        const int b = (total_subtokens + 255) / 256;
        build_starts_kernel<<<b, 256, 0, stream>>>(segs, starts, total_subtokens, n_nodes);
    }

    const int n_groups         = (n_nodes + SPG - 1) / SPG;
    const int groups_per_block = 256 / LPG;          // 8
    const int n_blocks         = (n_groups + groups_per_block - 1) / groups_per_block;

    SubTokenEmbedding_6734508720780_kernel<<<n_blocks, 256, 0, stream>>>(
        table, ids, segs, starts, out, total_subtokens, n_nodes);
}

// Round 3
// 69.644 us; speedup vs baseline: 1.4234x; 1.1823x over previous
//
#include <hip/hip_runtime.h>

// SubTokenEmbedding: fused embedding gather + sorted-segment sum pooling.
//
// out[s, :] = sum_{i : segs[i]==s} table[ids[i], :]     (segs sorted ascending)
//
// Three kernels per launch (all on `stream`, deterministic):
//   1) convert_table: f32 table -> bf16-packed table in d_ws (halves the
//      random-gather footprint; 8.2 MB fits much better in per-XCD L2).
//   2) build_starts:  starts[s] = lower_bound(segs, s), via scatter from
//      adjacent diffs of the sorted segs array.
//   3) main: one 32-lane group per SPG consecutive segments; reads its
//      subtoken range from starts[], scans with UNROLL-deep gather ILP,
//      accumulates the 128-wide row in f32 registers (lane l owns floats
//      [4l,4l+4)), plain-stores each segment (zeros for empties).
// No atomics; every output element written exactly once per launch, so the
// poisoned d_out needs no pre-zeroing.

#define H_EMB   128
#define LPG     32      // lanes per group (32 lanes x 4 floats = 128)
#define SPG     4       // segments per group
#define UNROLL  8       // table-row loads kept in flight per group
#define ROW_U2  32      // uint2 per bf16 row (128 bf16 = 256 B)

__device__ __forceinline__ unsigned f2bf_rne(float f) {
    unsigned u = __float_as_uint(f);
    return (u + 0x7FFFu + ((u >> 16) & 1u)) >> 16;   // round-to-nearest-even
}

__global__ __launch_bounds__(256)
void convert_table_kernel(const float* __restrict__ t, unsigned* __restrict__ ct,
                          int n_pairs)
{
    const int i = blockIdx.x * blockDim.x + threadIdx.x;
    if (i >= n_pairs) return;
    const float2 f = reinterpret_cast<const float2*>(t)[i];
    ct[i] = f2bf_rne(f.x) | (f2bf_rne(f.y) << 16);
}

__global__ __launch_bounds__(256)
void build_starts_kernel(const int* __restrict__ segs, int* __restrict__ starts,
                         int n, int n_nodes)
{
    const int i = blockIdx.x * blockDim.x + threadIdx.x;
    if (i >= n) return;
    const int s  = segs[i];
    const int sp = (i == 0) ? -1 : segs[i - 1];
    for (int seg = sp + 1; seg <= s; ++seg) starts[seg] = i;   // run-starts + gaps
    if (i == n - 1)
        for (int seg = s + 1; seg <= n_nodes; ++seg) starts[seg] = n;
}

// -------- bf16-table main kernel --------
__global__ __launch_bounds__(256)
void SubTokenEmbedding_6734508720780_kernel(
    const uint2* __restrict__ ctab,     // bf16-packed table, ROW_U2 uint2/row
    const int*   __restrict__ ids,
    const int*   __restrict__ segs,
    const int*   __restrict__ starts,   // [n_nodes+1]
    float*       __restrict__ out,
    int n_nodes)
{
    const int group = (int)((blockIdx.x * blockDim.x + threadIdx.x) / LPG);
    const int lane  = (int)(threadIdx.x & (LPG - 1));
    const int s0    = group * SPG;
    if (s0 >= n_nodes) return;
    const int s_end = min(s0 + SPG, n_nodes);

    const int beg = starts[s0];
    const int end = starts[s_end];

    const uint2* trow = ctab + lane;          // lane l reads uint2 #l of each row
    float*       orow = out  + (size_t)lane * 4;

    float4 acc = make_float4(0.f, 0.f, 0.f, 0.f);
    int cur = s0;

    // seg/id stream loaded 32 at a time (coalesced), distributed via shfl
    int sv = 0, iv = 0;
    if (beg + lane < end) { sv = segs[beg + lane]; iv = ids[beg + lane]; }

    for (int base = beg; base < end; base += LPG) {
        const int cnt = min(LPG, end - base);
        const int nb  = base + LPG;
        int sv2 = 0, iv2 = 0;
        if (nb + lane < end) { sv2 = segs[nb + lane]; iv2 = ids[nb + lane]; }

        for (int k = 0; k < cnt; k += UNROLL) {
            int s_a[UNROLL], id_a[UNROLL];
            #pragma unroll
            for (int u = 0; u < UNROLL; ++u) {
                s_a[u]  = __shfl(sv, k + u, LPG);
                id_a[u] = __shfl(iv, k + u, LPG);
            }
            // issue all gathers before consuming any (OOR u reads row 0: harmless)
            uint2 t[UNROLL];
            #pragma unroll
            for (int u = 0; u < UNROLL; ++u)
                t[u] = trow[(size_t)id_a[u] * ROW_U2];

            #pragma unroll
            for (int u = 0; u < UNROLL; ++u) {
                if (k + u < cnt) {
                    const int s = s_a[u];
                    if (s != cur) {
                        *reinterpret_cast<float4*>(orow + (size_t)cur * H_EMB) = acc;
                        const float4 zero = make_float4(0.f, 0.f, 0.f, 0.f);
                        for (int z = cur + 1; z < s; ++z)
                            *reinterpret_cast<float4*>(orow + (size_t)z * H_EMB) = zero;
                        acc = zero;
                        cur = s;
                    }
                    acc.x += __uint_as_float(t[u].x << 16);
                    acc.y += __uint_as_float(t[u].x & 0xFFFF0000u);
                    acc.z += __uint_as_float(t[u].y << 16);
                    acc.w += __uint_as_float(t[u].y & 0xFFFF0000u);
                }
            }
        }
        sv = sv2; iv = iv2;
    }

    *reinterpret_cast<float4*>(orow + (size_t)cur * H_EMB) = acc;
    const float4 zero = make_float4(0.f, 0.f, 0.f, 0.f);
    for (int z = cur + 1; z < s_end; ++z)
        *reinterpret_cast<float4*>(orow + (size_t)z * H_EMB) = zero;
}

// -------- f32 fallback (ws too small for bf16 table) --------
__global__ __launch_bounds__(256)
void subtok_f32_kernel(
    const float* __restrict__ table,
    const int*   __restrict__ ids,
    const int*   __restrict__ segs,
    const int*   __restrict__ starts,   // may be null -> binary search
    float*       __restrict__ out,
    int total_subtokens, int n_nodes)
{
    const int group = (int)((blockIdx.x * blockDim.x + threadIdx.x) / LPG);
    const int lane  = (int)(threadIdx.x & (LPG - 1));
    const int s0    = group * SPG;
    if (s0 >= n_nodes) return;
    const int s_end = min(s0 + SPG, n_nodes);

    int beg, end;
    if (starts) { beg = starts[s0]; end = starts[s_end]; }
    else {
        auto lower_bound = [&](int v) -> int {
            int lo = 0, hi = total_subtokens;
            while (lo < hi) { int m = (lo + hi) >> 1; if (segs[m] < v) lo = m + 1; else hi = m; }
            return lo;
        };
        beg = lower_bound(s0); end = lower_bound(s_end);
    }

    const float* trow = table + (size_t)lane * 4;
    float*       orow = out   + (size_t)lane * 4;
    float4 acc = make_float4(0.f, 0.f, 0.f, 0.f);
    int cur = s0;

    for (int j = beg; j < end; ++j) {
        const int s  = segs[j];
        const int id = ids[j];
        if (s != cur) {
            *reinterpret_cast<float4*>(orow + (size_t)cur * H_EMB) = acc;
            const float4 zero = make_float4(0.f, 0.f, 0.f, 0.f);
            for (int z = cur + 1; z < s; ++z)
                *reinterpret_cast<float4*>(orow + (size_t)z * H_EMB) = zero;
            acc = zero; cur = s;
        }
        const float4 t = *reinterpret_cast<const float4*>(trow + (size_t)id * H_EMB);
        acc.x += t.x; acc.y += t.y; acc.z += t.z; acc.w += t.w;
    }
    *reinterpret_cast<float4*>(orow + (size_t)cur * H_EMB) = acc;
    const float4 zero = make_float4(0.f, 0.f, 0.f, 0.f);
    for (int z = cur + 1; z < s_end; ++z)
        *reinterpret_cast<float4*>(orow + (size_t)z * H_EMB) = zero;
}

extern "C" void kernel_launch(void* const* d_in, const int* in_sizes, int n_in,
                              void* d_out, int out_size, void* d_ws, size_t ws_size,
                              hipStream_t stream) {
    const float* table = (const float*)d_in[0];
    const int*   ids   = (const int*)d_in[1];
    const int*   segs  = (const int*)d_in[2];
    float*       out   = (float*)d_out;

    const int total_subtokens = in_sizes[1];
    const int vocab           = in_sizes[0] / H_EMB;
    const int n_nodes         = out_size / H_EMB;    // out is [n_nodes, 128]

    const size_t starts_bytes = ((size_t)(n_nodes + 1) * sizeof(int) + 15) & ~(size_t)15;
    const size_t ctab_bytes   = (size_t)vocab * (H_EMB / 2) * sizeof(unsigned); // 256 B/row

    const int n_groups         = (n_nodes + SPG - 1) / SPG;
    const int groups_per_block = 256 / LPG;          // 8
    const int n_blocks         = (n_groups + groups_per_block - 1) / groups_per_block;

    int* starts = nullptr;
    if (ws_size >= starts_bytes) {
        starts = (int*)d_ws;
        const int b = (total_subtokens + 255) / 256;
        build_starts_kernel<<<b, 256, 0, stream>>>(segs, starts, total_subtokens, n_nodes);
    }

    if (starts && ws_size >= starts_bytes + ctab_bytes) {
        unsigned* ctab = (unsigned*)((char*)d_ws + starts_bytes);
        const int n_pairs = vocab * (H_EMB / 2);
        convert_table_kernel<<<(n_pairs + 255) / 256, 256, 0, stream>>>(table, ctab, n_pairs);
        SubTokenEmbedding_6734508720780_kernel<<<n_blocks, 256, 0, stream>>>(
            (const uint2*)ctab, ids, segs, starts, out, n_nodes);
    } else {
        subtok_f32_kernel<<<n_blocks, 256, 0, stream>>>(
            table, ids, segs, starts, out, total_subtokens, n_nodes);
    }
}

// Round 4
// 66.563 us; speedup vs baseline: 1.4893x; 1.0463x over previous
//
#include <hip/hip_runtime.h>

// SubTokenEmbedding: fused embedding gather + sorted-segment sum pooling.
//
// out[s, :] = sum_{i : segs[i]==s} table[ids[i], :]     (segs sorted ascending)
//
// Per launch (all on `stream`, deterministic):
//   1) prep_kernel (fused):
//        a) convert f32 table -> bf16-packed table in d_ws (halves the random
//           gather footprint: 8.2 MB, L2-friendly)
//        b) starts[s] = lower_bound(segs, s) via scatter from adjacent diffs
//   2) main: one 16-lane group per SPG consecutive segments. Each lane holds
//      uint4 = 16 B = 8 bf16 of the row -> one load instruction fetches a full
//      256 B row per group; 4 groups/wave x UNROLL=8 keeps 32 rows in flight
//      per wave. Accumulate in f32 registers, plain-store each segment
//      (zeros for empties). No atomics; every output element written exactly
//      once per launch, so the poisoned d_out needs no pre-zeroing.

#define H_EMB   128
#define LPG     16      // lanes per group (16 lanes x uint4 = 256 B bf16 row)
#define SPG     4       // segments per group
#define UNROLL  8       // table-row loads kept in flight per group
#define ROW_U4  16      // uint4 per bf16 row

__device__ __forceinline__ unsigned f2bf_rne(float f) {
    unsigned u = __float_as_uint(f);
    return (u + 0x7FFFu + ((u >> 16) & 1u)) >> 16;   // round-to-nearest-even
}

__global__ __launch_bounds__(256)
void prep_kernel(const float* __restrict__ t, unsigned* __restrict__ ct, int n_pairs,
                 const int* __restrict__ segs, int* __restrict__ starts,
                 int n, int n_nodes)
{
    const int i = blockIdx.x * blockDim.x + threadIdx.x;
    if (i < n_pairs) {
        const float2 f = reinterpret_cast<const float2*>(t)[i];
        ct[i] = f2bf_rne(f.x) | (f2bf_rne(f.y) << 16);
    }
    if (i < n) {
        const int s  = segs[i];
        const int sp = (i == 0) ? -1 : segs[i - 1];
        for (int seg = sp + 1; seg <= s; ++seg) starts[seg] = i;   // run-starts + gaps
        if (i == n - 1)
            for (int seg = s + 1; seg <= n_nodes; ++seg) starts[seg] = n;
    }
}

// -------- bf16-table main kernel --------
__global__ __launch_bounds__(256)
void SubTokenEmbedding_6734508720780_kernel(
    const uint4* __restrict__ ctab,     // bf16-packed table, ROW_U4 uint4/row
    const int*   __restrict__ ids,
    const int*   __restrict__ segs,
    const int*   __restrict__ starts,   // [n_nodes+1]
    float*       __restrict__ out,
    int n_nodes)
{
    const int group = (int)((blockIdx.x * blockDim.x + threadIdx.x) / LPG);
    const int lane  = (int)(threadIdx.x & (LPG - 1));
    const int s0    = group * SPG;
    if (s0 >= n_nodes) return;
    const int s_end = min(s0 + SPG, n_nodes);

    const int beg = starts[s0];
    const int end = starts[s_end];

    const uint4* trow = ctab + lane;          // lane l reads uint4 #l of each row
    float*       orow = out  + (size_t)lane * 8;

    float acc[8] = {0.f, 0.f, 0.f, 0.f, 0.f, 0.f, 0.f, 0.f};
    int cur = s0;

    // seg/id stream loaded LPG at a time (coalesced per group), shfl-distributed
    int sv = 0, iv = 0;
    if (beg + lane < end) { sv = segs[beg + lane]; iv = ids[beg + lane]; }

    for (int base = beg; base < end; base += LPG) {
        const int cnt = min(LPG, end - base);
        const int nb  = base + LPG;
        int sv2 = 0, iv2 = 0;
        if (nb + lane < end) { sv2 = segs[nb + lane]; iv2 = ids[nb + lane]; }

        for (int k = 0; k < cnt; k += UNROLL) {
            int s_a[UNROLL], id_a[UNROLL];
            #pragma unroll
            for (int u = 0; u < UNROLL; ++u) {
                s_a[u]  = __shfl(sv, k + u, LPG);
                id_a[u] = __shfl(iv, k + u, LPG);
            }
            // issue all gathers before consuming any (OOR u reads row 0: harmless)
            uint4 t[UNROLL];
            #pragma unroll
            for (int u = 0; u < UNROLL; ++u)
                t[u] = trow[(size_t)id_a[u] * ROW_U4];

            #pragma unroll
            for (int u = 0; u < UNROLL; ++u) {
                if (k + u < cnt) {
                    const int s = s_a[u];
                    if (s != cur) {
                        float4* o = reinterpret_cast<float4*>(orow + (size_t)cur * H_EMB);
                        o[0] = make_float4(acc[0], acc[1], acc[2], acc[3]);
                        o[1] = make_float4(acc[4], acc[5], acc[6], acc[7]);
                        #pragma unroll
                        for (int e = 0; e < 8; ++e) acc[e] = 0.f;
                        const float4 zero = make_float4(0.f, 0.f, 0.f, 0.f);
                        for (int z = cur + 1; z < s; ++z) {
                            float4* oz = reinterpret_cast<float4*>(orow + (size_t)z * H_EMB);
                            oz[0] = zero; oz[1] = zero;
                        }
                        cur = s;
                    }
                    acc[0] += __uint_as_float(t[u].x << 16);
                    acc[1] += __uint_as_float(t[u].x & 0xFFFF0000u);
                    acc[2] += __uint_as_float(t[u].y << 16);
                    acc[3] += __uint_as_float(t[u].y & 0xFFFF0000u);
                    acc[4] += __uint_as_float(t[u].z << 16);
                    acc[5] += __uint_as_float(t[u].z & 0xFFFF0000u);
                    acc[6] += __uint_as_float(t[u].w << 16);
                    acc[7] += __uint_as_float(t[u].w & 0xFFFF0000u);
                }
            }
        }
        sv = sv2; iv = iv2;
    }

    // final flush: cur, then zeros through s_end-1
    {
        float4* o = reinterpret_cast<float4*>(orow + (size_t)cur * H_EMB);
        o[0] = make_float4(acc[0], acc[1], acc[2], acc[3]);
        o[1] = make_float4(acc[4], acc[5], acc[6], acc[7]);
        const float4 zero = make_float4(0.f, 0.f, 0.f, 0.f);
        for (int z = cur + 1; z < s_end; ++z) {
            float4* oz = reinterpret_cast<float4*>(orow + (size_t)z * H_EMB);
            oz[0] = zero; oz[1] = zero;
        }
    }
}

// -------- f32 fallback (ws too small for bf16 table / starts) --------
__global__ __launch_bounds__(256)
void subtok_f32_kernel(
    const float* __restrict__ table,
    const int*   __restrict__ ids,
    const int*   __restrict__ segs,
    float*       __restrict__ out,
    int total_subtokens, int n_nodes)
{
    const int group = (int)((blockIdx.x * blockDim.x + threadIdx.x) / 32);
    const int lane  = (int)(threadIdx.x & 31);
    const int s0    = group * SPG;
    if (s0 >= n_nodes) return;
    const int s_end = min(s0 + SPG, n_nodes);

    auto lower_bound = [&](int v) -> int {
        int lo = 0, hi = total_subtokens;
        while (lo < hi) { int m = (lo + hi) >> 1; if (segs[m] < v) lo = m + 1; else hi = m; }
        return lo;
    };
    const int beg = lower_bound(s0);
    const int end = lower_bound(s_end);

    const float* trow = table + (size_t)lane * 4;
    float*       orow = out   + (size_t)lane * 4;
    float4 acc = make_float4(0.f, 0.f, 0.f, 0.f);
    int cur = s0;

    for (int j = beg; j < end; ++j) {
        const int s  = segs[j];
        const int id = ids[j];
        if (s != cur) {
            *reinterpret_cast<float4*>(orow + (size_t)cur * H_EMB) = acc;
            const float4 zero = make_float4(0.f, 0.f, 0.f, 0.f);
            for (int z = cur + 1; z < s; ++z)
                *reinterpret_cast<float4*>(orow + (size_t)z * H_EMB) = zero;
            acc = zero; cur = s;
        }
        const float4 t = *reinterpret_cast<const float4*>(trow + (size_t)id * H_EMB);
        acc.x += t.x; acc.y += t.y; acc.z += t.z; acc.w += t.w;
    }
    *reinterpret_cast<float4*>(orow + (size_t)cur * H_EMB) = acc;
    const float4 zero = make_float4(0.f, 0.f, 0.f, 0.f);
    for (int z = cur + 1; z < s_end; ++z)
        *reinterpret_cast<float4*>(orow + (size_t)z * H_EMB) = zero;
}

extern "C" void kernel_launch(void* const* d_in, const int* in_sizes, int n_in,
                              void* d_out, int out_size, void* d_ws, size_t ws_size,
                              hipStream_t stream) {
    const float* table = (const float*)d_in[0];
    const int*   ids   = (const int*)d_in[1];
    const int*   segs  = (const int*)d_in[2];
    float*       out   = (float*)d_out;

    const int total_subtokens = in_sizes[1];
    const int vocab           = in_sizes[0] / H_EMB;
    const int n_nodes         = out_size / H_EMB;    // out is [n_nodes, 128]

    const size_t starts_bytes = ((size_t)(n_nodes + 1) * sizeof(int) + 15) & ~(size_t)15;
    const size_t ctab_bytes   = (size_t)vocab * (H_EMB / 2) * sizeof(unsigned); // 256 B/row
    const int    n_pairs      = vocab * (H_EMB / 2);

    if (ws_size >= starts_bytes + ctab_bytes) {
        int*      starts = (int*)d_ws;
        unsigned* ctab   = (unsigned*)((char*)d_ws + starts_bytes);

        const int prep_n = max(n_pairs, total_subtokens);
        prep_kernel<<<(prep_n + 255) / 256, 256, 0, stream>>>(
            table, ctab, n_pairs, segs, starts, total_subtokens, n_nodes);

        const int n_groups         = (n_nodes + SPG - 1) / SPG;
        const int groups_per_block = 256 / LPG;          // 16
        const int n_blocks         = (n_groups + groups_per_block - 1) / groups_per_block;
        SubTokenEmbedding_6734508720780_kernel<<<n_blocks, 256, 0, stream>>>(
            (const uint4*)ctab, ids, segs, starts, out, n_nodes);
    } else {
        const int n_groups         = (n_nodes + SPG - 1) / SPG;
        const int groups_per_block = 256 / 32;
        const int n_blocks         = (n_groups + groups_per_block - 1) / groups_per_block;
        subtok_f32_kernel<<<n_blocks, 256, 0, stream>>>(
            table, ids, segs, out, total_subtokens, n_nodes);
    }
}

// Round 5
// 66.049 us; speedup vs baseline: 1.5008x; 1.0078x over previous
//
#include <hip/hip_runtime.h>

// SubTokenEmbedding: fused embedding gather + sorted-segment sum pooling.
//
// out[s, :] = sum_{i : segs[i]==s} table[ids[i], :]     (segs sorted ascending)
//
// Per launch (all on `stream`, deterministic):
//   1) prep_kernel (fused):
//        a) convert f32 table -> bf16-packed table in d_ws (halves the random
//           gather footprint: 8.2 MB, L2-friendly)
//        b) starts[s] = lower_bound(segs, s) via scatter from adjacent diffs
//   2) main: ONE FULL WAVE (64 lanes) per SPG consecutive segments -> zero
//      exec-mask divergence. Each lane holds uint = 4 B = 2 bf16 of the row;
//      one load instruction fetches a full 256 B row coalesced. UNROLL=16
//      rows in flight per wave. seg/id values are pulled from the batch
//      registers with v_readlane (uniform index) into SGPRs, so the
//      segment-flush compare and loop guards are SCALAR branches; the vector
//      pipe only unpacks and accumulates. Accumulate in f32 (2 floats/lane),
//      plain-store each segment (zeros for empties). No atomics; every output
//      element written exactly once per launch, so the poisoned d_out needs
//      no pre-zeroing.

#define H_EMB   128
#define SPG     8       // segments per wave
#define UNROLL  16      // table-row loads kept in flight per wave
#define ROW_U1  64      // uint per bf16 row (64 x 4 B = 256 B)

__device__ __forceinline__ unsigned f2bf_rne(float f) {
    unsigned u = __float_as_uint(f);
    return (u + 0x7FFFu + ((u >> 16) & 1u)) >> 16;   // round-to-nearest-even
}

__global__ __launch_bounds__(256)
void prep_kernel(const float* __restrict__ t, unsigned* __restrict__ ct, int n_pairs,
                 const int* __restrict__ segs, int* __restrict__ starts,
                 int n, int n_nodes)
{
    const int i = blockIdx.x * blockDim.x + threadIdx.x;
    if (i < n_pairs) {
        const float2 f = reinterpret_cast<const float2*>(t)[i];
        ct[i] = f2bf_rne(f.x) | (f2bf_rne(f.y) << 16);
    }
    if (i < n) {
        const int s  = segs[i];
        const int sp = (i == 0) ? -1 : segs[i - 1];
        for (int seg = sp + 1; seg <= s; ++seg) starts[seg] = i;   // run-starts + gaps
        if (i == n - 1)
            for (int seg = s + 1; seg <= n_nodes; ++seg) starts[seg] = n;
    }
}

// -------- bf16-table main kernel: one wave per SPG segments --------
__global__ __launch_bounds__(256)
void SubTokenEmbedding_6734508720780_kernel(
    const unsigned* __restrict__ ctab,   // bf16-packed table, ROW_U1 uint/row
    const int*      __restrict__ ids,
    const int*      __restrict__ segs,
    const int*      __restrict__ starts, // [n_nodes+1]
    float*          __restrict__ out,
    int n_nodes)
{
    const int wave = (int)((blockIdx.x * blockDim.x + threadIdx.x) >> 6);
    const int lane = (int)(threadIdx.x & 63);
    const int s0   = wave * SPG;
    if (s0 >= n_nodes) return;
    const int s_end = min(s0 + SPG, n_nodes);

    const int beg = starts[s0];
    const int end = starts[s_end];

    const unsigned* trow = ctab + lane;          // lane l reads uint #l of each row
    float*          orow = out  + lane * 2;      // lane l owns floats 2l, 2l+1

    float accx = 0.f, accy = 0.f;
    int cur = s0;

    // seg/id stream loaded 64 at a time (coalesced 256 B), extracted via readlane
    int sv = 0, iv = 0;
    if (beg + lane < end) { sv = segs[beg + lane]; iv = ids[beg + lane]; }

    for (int base = beg; base < end; base += 64) {
        const int cnt = min(64, end - base);
        const int nb  = base + 64;
        int sv2 = 0, iv2 = 0;
        if (nb + lane < end) { sv2 = segs[nb + lane]; iv2 = ids[nb + lane]; }

        for (int k = 0; k < cnt; k += UNROLL) {
            int s_a[UNROLL], id_a[UNROLL];
            #pragma unroll
            for (int u = 0; u < UNROLL; ++u) {
                s_a[u]  = __builtin_amdgcn_readlane(sv, k + u);   // -> SGPR
                id_a[u] = __builtin_amdgcn_readlane(iv, k + u);   // -> SGPR
            }
            // issue all gathers before consuming any (OOR u reads row 0: harmless)
            unsigned tv[UNROLL];
            #pragma unroll
            for (int u = 0; u < UNROLL; ++u)
                tv[u] = trow[(size_t)id_a[u] * ROW_U1];

            #pragma unroll
            for (int u = 0; u < UNROLL; ++u) {
                if (k + u < cnt) {                       // scalar branch
                    const int s = s_a[u];
                    if (s != cur) {                      // scalar branch
                        *reinterpret_cast<float2*>(orow + (size_t)cur * H_EMB) =
                            make_float2(accx, accy);
                        accx = 0.f; accy = 0.f;
                        for (int z = cur + 1; z < s; ++z)
                            *reinterpret_cast<float2*>(orow + (size_t)z * H_EMB) =
                                make_float2(0.f, 0.f);
                        cur = s;
                    }
                    accx += __uint_as_float(tv[u] << 16);
                    accy += __uint_as_float(tv[u] & 0xFFFF0000u);
                }
            }
        }
        sv = sv2; iv = iv2;
    }

    // final flush: cur, then zeros through s_end-1
    *reinterpret_cast<float2*>(orow + (size_t)cur * H_EMB) = make_float2(accx, accy);
    for (int z = cur + 1; z < s_end; ++z)
        *reinterpret_cast<float2*>(orow + (size_t)z * H_EMB) = make_float2(0.f, 0.f);
}

// -------- f32 fallback (ws too small for bf16 table / starts) --------
__global__ __launch_bounds__(256)
void subtok_f32_kernel(
    const float* __restrict__ table,
    const int*   __restrict__ ids,
    const int*   __restrict__ segs,
    float*       __restrict__ out,
    int total_subtokens, int n_nodes)
{
    const int group = (int)((blockIdx.x * blockDim.x + threadIdx.x) / 32);
    const int lane  = (int)(threadIdx.x & 31);
    const int s0    = group * SPG;
    if (s0 >= n_nodes) return;
    const int s_end = min(s0 + SPG, n_nodes);

    auto lower_bound = [&](int v) -> int {
        int lo = 0, hi = total_subtokens;
        while (lo < hi) { int m = (lo + hi) >> 1; if (segs[m] < v) lo = m + 1; else hi = m; }
        return lo;
    };
    const int beg = lower_bound(s0);
    const int end = lower_bound(s_end);

    const float* trow = table + (size_t)lane * 4;
    float*       orow = out   + (size_t)lane * 4;
    float4 acc = make_float4(0.f, 0.f, 0.f, 0.f);
    int cur = s0;

    for (int j = beg; j < end; ++j) {
        const int s  = segs[j];
        const int id = ids[j];
        if (s != cur) {
            *reinterpret_cast<float4*>(orow + (size_t)cur * H_EMB) = acc;
            const float4 zero = make_float4(0.f, 0.f, 0.f, 0.f);
            for (int z = cur + 1; z < s; ++z)
                *reinterpret_cast<float4*>(orow + (size_t)z * H_EMB) = zero;
            acc = zero; cur = s;
        }
        const float4 t = *reinterpret_cast<const float4*>(trow + (size_t)id * H_EMB);
        acc.x += t.x; acc.y += t.y; acc.z += t.z; acc.w += t.w;
    }
    *reinterpret_cast<float4*>(orow + (size_t)cur * H_EMB) = acc;
    const float4 zero = make_float4(0.f, 0.f, 0.f, 0.f);
    for (int z = cur + 1; z < s_end; ++z)
        *reinterpret_cast<float4*>(orow + (size_t)z * H_EMB) = zero;
}

extern "C" void kernel_launch(void* const* d_in, const int* in_sizes, int n_in,
                              void* d_out, int out_size, void* d_ws, size_t ws_size,
                              hipStream_t stream) {
    const float* table = (const float*)d_in[0];
    const int*   ids   = (const int*)d_in[1];
    const int*   segs  = (const int*)d_in[2];
    float*       out   = (float*)d_out;

    const int total_subtokens = in_sizes[1];
    const int vocab           = in_sizes[0] / H_EMB;
    const int n_nodes         = out_size / H_EMB;    // out is [n_nodes, 128]

    const size_t starts_bytes = ((size_t)(n_nodes + 1) * sizeof(int) + 15) & ~(size_t)15;
    const size_t ctab_bytes   = (size_t)vocab * (H_EMB / 2) * sizeof(unsigned); // 256 B/row
    const int    n_pairs      = vocab * (H_EMB / 2);

    if (ws_size >= starts_bytes + ctab_bytes) {
        int*      starts = (int*)d_ws;
        unsigned* ctab   = (unsigned*)((char*)d_ws + starts_bytes);

        const int prep_n = max(n_pairs, total_subtokens);
        prep_kernel<<<(prep_n + 255) / 256, 256, 0, stream>>>(
            table, ctab, n_pairs, segs, starts, total_subtokens, n_nodes);

        const int n_waves  = (n_nodes + SPG - 1) / SPG;
        const int n_blocks = (n_waves + 3) / 4;          // 4 waves per 256-thread block
        SubTokenEmbedding_6734508720780_kernel<<<n_blocks, 256, 0, stream>>>(
            ctab, ids, segs, starts, out, n_nodes);
    } else {
        const int n_groups = (n_nodes + SPG - 1) / SPG;
        const int n_blocks = (n_groups + 7) / 8;
        subtok_f32_kernel<<<n_blocks, 256, 0, stream>>>(
            table, ids, segs, out, total_subtokens, n_nodes);
    }
}